// Round 4
// 568.898 us; speedup vs baseline: 1.0015x; 1.0015x over previous
//
#include <hip/hip_runtime.h>
#include <stdint.h>

#define NSEQ 512
#define DPAIR 128
#define NN (NSEQ*NSEQ)        // 262144 positions
#define LDPAD 136             // 128 + 8 pad: keeps 16B ds alignment, ~2-way conflicts max

typedef unsigned short u16;
typedef __attribute__((ext_vector_type(8))) short bf16x8;   // 8 bf16 = 4 VGPRs
typedef __attribute__((ext_vector_type(4))) float f32x4;

__device__ __forceinline__ float bf2f(u16 h){ return __uint_as_float(((uint32_t)h)<<16); }
__device__ __forceinline__ u16 f2bf(float f){
  uint32_t u = __float_as_uint(f);
  u += 0x7fffu + ((u>>16)&1u);          // RNE
  return (u16)(u>>16);
}
// HW packed f32->bf16 (RNE), 1 VALU op per 2 elements; bit-identical to f2bf for finite inputs
__device__ __forceinline__ uint32_t cvtpk(float lo, float hi){
  uint32_t r;
  asm("v_cvt_pk_bf16_f32 %0, %1, %2" : "=v"(r) : "v"(lo), "v"(hi));
  return r;
}
__device__ __forceinline__ float sigmoidf_(float x){ return 1.0f/(1.0f+__expf(-x)); }

// stage 64 rows x 128 cols of fp32 (row-major, k contiguous) -> bf16 LDS [64][LDPAD]
__device__ __forceinline__ void stage_w64(const float* __restrict__ src, u16* wb, int t){
  const float4* ws = (const float4*)src;
  #pragma unroll
  for (int i=0;i<8;i++){
    int e4 = i*256 + t; int r = e4>>5, c4 = e4&31;
    float4 v = ws[e4];
    uint2 pk;
    pk.x = cvtpk(v.x, v.y);
    pk.y = cvtpk(v.z, v.w);
    *(uint2*)&wb[r*LDPAD + c4*4] = pk;
  }
}

// 64x64x128 GEMM: D[pos][n] = sum_k A[pos][k]*W[n][k]; per-wave 32x32 tile (2x2 MFMAs x 4 k-steps)
__device__ __forceinline__ void gemm_64x64(const u16* A, const u16* W,
                                           int wm, int wn, int fr, int fq,
                                           f32x4 (&acc)[2][2]){
  #pragma unroll
  for (int kk=0;kk<4;kk++){
    bf16x8 aF[2], bF[2];
    #pragma unroll
    for (int mi=0;mi<2;mi++) aF[mi] = *(const bf16x8*)(A + (wm+mi*16+fr)*LDPAD + kk*32 + fq*8);
    #pragma unroll
    for (int ni=0;ni<2;ni++) bF[ni] = *(const bf16x8*)(W + (wn+ni*16+fr)*LDPAD + kk*32 + fq*8);
    #pragma unroll
    for (int mi=0;mi<2;mi++)
      #pragma unroll
      for (int ni=0;ni<2;ni++)
        acc[mi][ni] = __builtin_amdgcn_mfma_f32_16x16x32_bf16(aF[mi], bF[ni], acc[mi][ni], 0, 0, 0);
  }
}

// K1: LN(z) -> P,G projections -> a,b (d-major bf16) ; g = sigmoid(z@w_g^T+b_g) ([p][d] bf16)
__global__ __launch_bounds__(256) void k1_proj(
    const float* __restrict__ z, const float* __restrict__ mask,
    const float* __restrict__ w_ab_p, const float* __restrict__ b_ab_p,
    const float* __restrict__ w_ab_g, const float* __restrict__ b_ab_g,
    const float* __restrict__ w_g, const float* __restrict__ b_g,
    const float* __restrict__ ln_g, const float* __restrict__ ln_b,
    u16* __restrict__ a_t, u16* __restrict__ b_t, u16* __restrict__ g_out)
{
  __shared__ u16 zr[64*LDPAD];   // raw z, bf16
  __shared__ u16 zn[64*LDPAD];   // LN(z), bf16
  __shared__ u16 wb[64*LDPAD];   // weight panel / output transpose buffer
  __shared__ float lng[DPAIR], lnb[DPAIR], msk[64];

  const int t = threadIdx.x;
  const int p0 = blockIdx.x * 64;
  const int lane = t & 63, wv = t >> 6;
  const int wm = (wv >> 1) * 32, wn = (wv & 1) * 32;
  const int fr = lane & 15, fq = lane >> 4;

  if (t < DPAIR){ lng[t] = ln_g[t]; lnb[t] = ln_b[t]; }
  else if (t < DPAIR + 64) msk[t - DPAIR] = mask[p0 + t - DPAIR];

  { // stage raw z tile (64 pos x 128 ch, contiguous) -> bf16
    const float4* zs = (const float4*)(z + (size_t)p0 * DPAIR);
    #pragma unroll
    for (int i=0;i<8;i++){
      int e4 = i*256 + t; int pos = e4>>5, c4 = e4&31;
      float4 v = zs[e4];
      uint2 pk;
      pk.x = cvtpk(v.x, v.y);
      pk.y = cvtpk(v.z, v.w);
      *(uint2*)&zr[pos*LDPAD + c4*4] = pk;
    }
  }
  __syncthreads();
  { // layernorm -> zn ; 4 threads per position
    int pos = t>>2, q = t&3;
    float s=0.f, s2=0.f;
    #pragma unroll
    for (int j=0;j<32;j++){ float v = bf2f(zr[pos*LDPAD + q*32 + j]); s += v; s2 += v*v; }
    s  += __shfl_xor(s, 1);  s2 += __shfl_xor(s2, 1);
    s  += __shfl_xor(s, 2);  s2 += __shfl_xor(s2, 2);
    float mu  = s * (1.f/128.f);
    float var = s2 * (1.f/128.f) - mu*mu;
    float rs  = rsqrtf(var + 1e-5f);
    #pragma unroll
    for (int j=0;j<32;j++){
      int c = q*32 + j;
      float v = bf2f(zr[pos*LDPAD + c]);
      zn[pos*LDPAD + c] = f2bf((v - mu)*rs*lng[c] + lnb[c]);
    }
  }

  // a/b: 4 n-tiles of 64 over 256 outputs (nt 0,1 -> a ; 2,3 -> b)
  for (int nt=0; nt<4; nt++){
    __syncthreads();
    stage_w64(w_ab_p + nt*64*DPAIR, wb, t);
    __syncthreads();
    f32x4 accP[2][2] = {};
    gemm_64x64(zn, wb, wm, wn, fr, fq, accP);
    __syncthreads();
    stage_w64(w_ab_g + nt*64*DPAIR, wb, t);
    __syncthreads();
    f32x4 accG[2][2] = {};
    gemm_64x64(zn, wb, wm, wn, fr, fq, accG);
    __syncthreads();
    // combine P*sigmoid(G)*mask, transpose to [n][pos] (rows padded to 72) in wb
    #pragma unroll
    for (int mi=0;mi<2;mi++)
      #pragma unroll
      for (int ni=0;ni<2;ni++)
        #pragma unroll
        for (int r=0;r<4;r++){
          int pos = wm + mi*16 + fq*4 + r;
          int nl  = wn + ni*16 + fr;
          int ng  = nt*64 + nl;
          float p  = accP[mi][ni][r] + b_ab_p[ng];
          float gg = accG[mi][ni][r] + b_ab_g[ng];
          wb[nl*72 + pos] = f2bf(p * sigmoidf_(gg) * msk[pos]);
        }
    __syncthreads();
    u16* dst = (nt < 2) ? a_t : b_t;
    int dbase = (nt & 1) * 64;
    #pragma unroll
    for (int i=0;i<2;i++){ // 64 d-rows x 64 pos, 16B vector stores
      int e8 = i*256 + t; int dl = e8>>3, pc = e8&7;
      uint4 v = *(const uint4*)&wb[dl*72 + pc*8];
      *(uint4*)&dst[(size_t)(dbase+dl)*NN + p0 + pc*8] = v;
    }
  }

  // gate g = sigmoid(z @ w_g^T + b_g), raw-z input
  for (int nt=0; nt<2; nt++){
    __syncthreads();
    stage_w64(w_g + nt*64*DPAIR, wb, t);
    __syncthreads();
    f32x4 acc[2][2] = {};
    gemm_64x64(zr, wb, wm, wn, fr, fq, acc);
    #pragma unroll
    for (int mi=0;mi<2;mi++)
      #pragma unroll
      for (int ni=0;ni<2;ni++)
        #pragma unroll
        for (int r=0;r<4;r++){
          int pos = wm + mi*16 + fq*4 + r;
          int ng  = nt*64 + wn + ni*16 + fr;
          g_out[(size_t)(p0+pos)*DPAIR + ng] = f2bf(sigmoidf_(acc[mi][ni][r] + b_g[ng]));
        }
  }
}

// K2: x[i,j,d] = sum_k a[i,k,d]*b[j,k,d] -> 128 GEMMs (512^3) C = A*B^T, both k-contiguous
__global__ __launch_bounds__(256) void k2_einsum(
    const u16* __restrict__ a_t, const u16* __restrict__ b_t, u16* __restrict__ x_t)
{
  __shared__ u16 As[128*40];   // 128 rows x (32 k + 8 pad)
  __shared__ u16 Bs[128*40];
  const int t = threadIdx.x;
  const int d  = blockIdx.z;
  const int i0 = blockIdx.x * 128;
  const int j0 = blockIdx.y * 128;
  const u16* Ag = a_t + (size_t)d*NN + (size_t)i0*NSEQ;
  const u16* Bg = b_t + (size_t)d*NN + (size_t)j0*NSEQ;

  const int lane = t & 63, wv = t >> 6;
  const int wm = (wv >> 1) * 64, wn = (wv & 1) * 64;
  const int fr = lane & 15, fq = lane >> 4;

  f32x4 acc[4][4] = {};

  for (int k0 = 0; k0 < NSEQ; k0 += 32){
    __syncthreads();
    #pragma unroll
    for (int i=0;i<2;i++){
      int e = i*256 + t; int r = e>>2, c8 = e&3;
      uint4 va = *(const uint4*)(Ag + (size_t)r*NSEQ + k0 + c8*8);
      *(uint4*)&As[r*40 + c8*8] = va;
      uint4 vb = *(const uint4*)(Bg + (size_t)r*NSEQ + k0 + c8*8);
      *(uint4*)&Bs[r*40 + c8*8] = vb;
    }
    __syncthreads();
    bf16x8 aF[4], bF[4];
    #pragma unroll
    for (int mi=0;mi<4;mi++) aF[mi] = *(const bf16x8*)&As[(wm + mi*16 + fr)*40 + fq*8];
    #pragma unroll
    for (int ni=0;ni<4;ni++) bF[ni] = *(const bf16x8*)&Bs[(wn + ni*16 + fr)*40 + fq*8];
    #pragma unroll
    for (int mi=0;mi<4;mi++)
      #pragma unroll
      for (int ni=0;ni<4;ni++)
        acc[mi][ni] = __builtin_amdgcn_mfma_f32_16x16x32_bf16(aF[mi], bF[ni], acc[mi][ni], 0, 0, 0);
  }
  u16* Xg = x_t + (size_t)d*NN;
  #pragma unroll
  for (int mi=0;mi<4;mi++)
    #pragma unroll
    for (int ni=0;ni<4;ni++)
      #pragma unroll
      for (int r=0;r<4;r++){
        int row = i0 + wm + mi*16 + fq*4 + r;
        int col = j0 + wn + ni*16 + fr;
        Xg[(size_t)row*NSEQ + col] = f2bf(acc[mi][ni][r]);
      }
}

// K3: out = g * (LN(x) @ w_z^T + b_z), fp32 out
__global__ __launch_bounds__(256) void k3_out(
    const u16* __restrict__ x_t, const u16* __restrict__ g_in,
    const float* __restrict__ w_z, const float* __restrict__ b_z,
    const float* __restrict__ ln_g, const float* __restrict__ ln_b,
    float* __restrict__ out)
{
  __shared__ u16 xs[64*LDPAD];      // 64 pos x 128 d
  __shared__ u16 wz[DPAIR*LDPAD];   // 128 c x 128 d
  __shared__ float lng[DPAIR], lnb[DPAIR], bzs[DPAIR];

  const int t = threadIdx.x;
  const int p0 = blockIdx.x * 64;
  if (t < DPAIR){ lng[t] = ln_g[t]; lnb[t] = ln_b[t]; bzs[t] = b_z[t]; }

  { // stage w_z -> bf16
    const float4* ws = (const float4*)w_z;
    #pragma unroll
    for (int i=0;i<16;i++){
      int e4 = i*256 + t; int r = e4>>5, c4 = e4&31;
      float4 v = ws[e4];
      uint2 pk;
      pk.x = cvtpk(v.x, v.y);
      pk.y = cvtpk(v.z, v.w);
      *(uint2*)&wz[r*LDPAD + c4*4] = pk;
    }
  }
  { // transpose-stage x: xs[pos][d] <- x_t[d][p0+pos] (coalesced 8B global reads)
    #pragma unroll
    for (int i=0;i<8;i++){
      int e = i*256 + t; int dd = e>>4, pc = e&15;
      uint2 v = *(const uint2*)(x_t + (size_t)dd*NN + p0 + pc*4);
      int pb = pc*4;
      xs[(pb+0)*LDPAD + dd] = (u16)(v.x & 0xffffu);
      xs[(pb+1)*LDPAD + dd] = (u16)(v.x >> 16);
      xs[(pb+2)*LDPAD + dd] = (u16)(v.y & 0xffffu);
      xs[(pb+3)*LDPAD + dd] = (u16)(v.y >> 16);
    }
  }
  __syncthreads();
  { // layernorm over d, in place
    int pos = t>>2, q = t&3;
    float s=0.f, s2=0.f;
    #pragma unroll
    for (int j=0;j<32;j++){ float v = bf2f(xs[pos*LDPAD + q*32 + j]); s += v; s2 += v*v; }
    s  += __shfl_xor(s, 1);  s2 += __shfl_xor(s2, 1);
    s  += __shfl_xor(s, 2);  s2 += __shfl_xor(s2, 2);
    float mu  = s * (1.f/128.f);
    float var = s2 * (1.f/128.f) - mu*mu;
    float rs  = rsqrtf(var + 1e-5f);
    #pragma unroll
    for (int j=0;j<32;j++){
      int c = q*32 + j;
      float v = bf2f(xs[pos*LDPAD + c]);
      xs[pos*LDPAD + c] = f2bf((v - mu)*rs*lng[c] + lnb[c]);
    }
  }
  __syncthreads();
  // GEMM: 64 pos x 128 c x 128 d ; wave tile 32x64
  const int lane = t & 63, wv = t >> 6;
  const int wm = (wv >> 1) * 32, wn = (wv & 1) * 64;
  const int fr = lane & 15, fq = lane >> 4;
  f32x4 acc[2][4] = {};
  #pragma unroll
  for (int kk=0;kk<4;kk++){
    bf16x8 aF[2], bF[4];
    #pragma unroll
    for (int mi=0;mi<2;mi++) aF[mi] = *(const bf16x8*)&xs[(wm+mi*16+fr)*LDPAD + kk*32 + fq*8];
    #pragma unroll
    for (int ni=0;ni<4;ni++) bF[ni] = *(const bf16x8*)&wz[(wn+ni*16+fr)*LDPAD + kk*32 + fq*8];
    #pragma unroll
    for (int mi=0;mi<2;mi++)
      #pragma unroll
      for (int ni=0;ni<4;ni++)
        acc[mi][ni] = __builtin_amdgcn_mfma_f32_16x16x32_bf16(aF[mi], bF[ni], acc[mi][ni], 0, 0, 0);
  }
  #pragma unroll
  for (int mi=0;mi<2;mi++)
    #pragma unroll
    for (int ni=0;ni<4;ni++)
      #pragma unroll
      for (int r=0;r<4;r++){
        int pos = wm + mi*16 + fq*4 + r;
        int c   = wn + ni*16 + fr;
        float gv = bf2f(g_in[(size_t)(p0+pos)*DPAIR + c]);
        out[(size_t)(p0+pos)*DPAIR + c] = gv * (acc[mi][ni][r] + bzs[c]);
      }
}

extern "C" void kernel_launch(void* const* d_in, const int* in_sizes, int n_in,
                              void* d_out, int out_size, void* d_ws, size_t ws_size,
                              hipStream_t stream)
{
  const float* z        = (const float*)d_in[0];
  const float* mask     = (const float*)d_in[1];
  const float* w_ab_p   = (const float*)d_in[2];
  const float* b_ab_p   = (const float*)d_in[3];
  const float* w_ab_g   = (const float*)d_in[4];
  const float* b_ab_g   = (const float*)d_in[5];
  const float* w_g      = (const float*)d_in[6];
  const float* b_g      = (const float*)d_in[7];
  const float* w_z      = (const float*)d_in[8];
  const float* b_z      = (const float*)d_in[9];
  const float* ln_in_g  = (const float*)d_in[10];
  const float* ln_in_b  = (const float*)d_in[11];
  const float* ln_out_g = (const float*)d_in[12];
  const float* ln_out_b = (const float*)d_in[13];
  float* out = (float*)d_out;

  const size_t plane = (size_t)DPAIR * NN;            // 33.5M elems
  if (ws_size < 4 * plane * sizeof(u16)) return;      // need 256 MB scratch

  u16* a_t = (u16*)d_ws;            // [128][512][512] bf16, a[i,k,d] -> a_t[d][i*512+k]
  u16* b_t = a_t + plane;           // same, b
  u16* g_b = b_t + plane;           // [pos][128] bf16 gate
  u16* x_t = g_b + plane;           // [128][512][512] bf16 einsum result

  k1_proj<<<dim3(NN/64), dim3(256), 0, stream>>>(
      z, mask, w_ab_p, b_ab_p, w_ab_g, b_ab_g, w_g, b_g, ln_in_g, ln_in_b, a_t, b_t, g_b);
  k2_einsum<<<dim3(4, 4, DPAIR), dim3(256), 0, stream>>>(a_t, b_t, x_t);
  k3_out<<<dim3(NN/64), dim3(256), 0, stream>>>(x_t, g_b, w_z, b_z, ln_out_g, ln_out_b, out);
}

// Round 5
// 567.554 us; speedup vs baseline: 1.0039x; 1.0024x over previous
//
#include <hip/hip_runtime.h>
#include <stdint.h>

#define NSEQ 512
#define DPAIR 128
#define NN (NSEQ*NSEQ)        // 262144 positions
#define LDPAD 136             // 128 + 8 pad: keeps 16B ds alignment, ~2-way conflicts max

typedef unsigned short u16;
typedef __attribute__((ext_vector_type(8))) short bf16x8;   // 8 bf16 = 4 VGPRs
typedef __attribute__((ext_vector_type(4))) float f32x4;

__device__ __forceinline__ float bf2f(u16 h){ return __uint_as_float(((uint32_t)h)<<16); }
__device__ __forceinline__ u16 f2bf(float f){
  uint32_t u = __float_as_uint(f);
  u += 0x7fffu + ((u>>16)&1u);          // RNE
  return (u16)(u>>16);
}
// HW packed f32->bf16 (RNE), 1 VALU op per 2 elements; bit-identical to f2bf for finite inputs
__device__ __forceinline__ uint32_t cvtpk(float lo, float hi){
  uint32_t r;
  asm("v_cvt_pk_bf16_f32 %0, %1, %2" : "=v"(r) : "v"(lo), "v"(hi));
  return r;
}
__device__ __forceinline__ float sigmoidf_(float x){ return 1.0f/(1.0f+__expf(-x)); }

// K1: gate gemm (raw z, 128-row panel) -> in-place LN -> 4x merged P/G gemms -> direct a/b stores
// barriers: 11 per block (was 29); stage phases: 5 (was 10)
__global__ __launch_bounds__(256) void k1_proj(
    const float* __restrict__ z, const float* __restrict__ mask,
    const float* __restrict__ w_ab_p, const float* __restrict__ b_ab_p,
    const float* __restrict__ w_ab_g, const float* __restrict__ b_ab_g,
    const float* __restrict__ w_g, const float* __restrict__ b_g,
    const float* __restrict__ ln_g, const float* __restrict__ ln_b,
    u16* __restrict__ a_t, u16* __restrict__ b_t, u16* __restrict__ g_out)
{
  __shared__ u16 zr[64*LDPAD];     // z tile, bf16 (raw, then LN'd in place)
  __shared__ u16 wb[128*LDPAD];    // weight panel(s): gate 128 rows, or P[0:64)+G[64:128)
  __shared__ float lng[DPAIR], lnb[DPAIR], msk[64];

  const int t = threadIdx.x;
  const int p0 = blockIdx.x * 64;
  const int lane = t & 63, wv = t >> 6;
  const int fr = lane & 15, fq = lane >> 4;

  if (t < DPAIR){ lng[t] = ln_g[t]; lnb[t] = ln_b[t]; }
  else if (t < DPAIR + 64) msk[t - DPAIR] = mask[p0 + t - DPAIR];

  { // stage raw z tile (64 pos x 128 ch, contiguous) -> bf16
    const float4* zs = (const float4*)(z + (size_t)p0 * DPAIR);
    #pragma unroll
    for (int i=0;i<8;i++){
      int e4 = i*256 + t; int pos = e4>>5, c4 = e4&31;
      float4 v = zs[e4];
      uint2 pk;
      pk.x = cvtpk(v.x, v.y);
      pk.y = cvtpk(v.z, v.w);
      *(uint2*)&zr[pos*LDPAD + c4*4] = pk;
    }
  }
  { // stage w_g: all 128 rows -> wb
    const float4* ws = (const float4*)w_g;
    #pragma unroll
    for (int i=0;i<16;i++){
      int e4 = i*256 + t; int r = e4>>5, c4 = e4&31;
      float4 v = ws[e4];
      uint2 pk;
      pk.x = cvtpk(v.x, v.y);
      pk.y = cvtpk(v.z, v.w);
      *(uint2*)&wb[r*LDPAD + c4*4] = pk;
    }
  }
  __syncthreads();

  { // gate gemm: 64 pos x 128 k x 128 out, raw z ; wave tile 32x64
    const int wm = (wv>>1)*32, wn2 = (wv&1)*64;
    f32x4 acc[2][4] = {};
    #pragma unroll
    for (int kk=0;kk<4;kk++){
      bf16x8 aF[2], bF[4];
      #pragma unroll
      for (int mi=0;mi<2;mi++) aF[mi] = *(const bf16x8*)&zr[(wm+mi*16+fr)*LDPAD + kk*32 + fq*8];
      #pragma unroll
      for (int ni=0;ni<4;ni++) bF[ni] = *(const bf16x8*)&wb[(wn2+ni*16+fr)*LDPAD + kk*32 + fq*8];
      #pragma unroll
      for (int mi=0;mi<2;mi++)
        #pragma unroll
        for (int ni=0;ni<4;ni++)
          acc[mi][ni] = __builtin_amdgcn_mfma_f32_16x16x32_bf16(aF[mi], bF[ni], acc[mi][ni], 0, 0, 0);
    }
    // g stores, baseline layout g_out[pos][c]
    #pragma unroll
    for (int mi=0;mi<2;mi++)
      #pragma unroll
      for (int ni=0;ni<4;ni++){
        int ng = wn2 + ni*16 + fr;
        float bg = b_g[ng];
        #pragma unroll
        for (int r=0;r<4;r++){
          int pos = wm + mi*16 + fq*4 + r;
          g_out[(size_t)(p0+pos)*DPAIR + ng] = f2bf(sigmoidf_(acc[mi][ni][r] + bg));
        }
      }
  }
  __syncthreads();   // gate reads of zr/wb complete

  { // layernorm in place on zr ; 4 threads per position (same math as baseline zr->zn)
    int pos = t>>2, q = t&3;
    float s=0.f, s2=0.f;
    #pragma unroll
    for (int j=0;j<32;j++){ float v = bf2f(zr[pos*LDPAD + q*32 + j]); s += v; s2 += v*v; }
    s  += __shfl_xor(s, 1);  s2 += __shfl_xor(s2, 1);
    s  += __shfl_xor(s, 2);  s2 += __shfl_xor(s2, 2);
    float mu  = s * (1.f/128.f);
    float var = s2 * (1.f/128.f) - mu*mu;
    float rs  = rsqrtf(var + 1e-5f);
    #pragma unroll
    for (int j=0;j<32;j++){
      int c = q*32 + j;
      float v = bf2f(zr[pos*LDPAD + c]);
      zr[pos*LDPAD + c] = f2bf((v - mu)*rs*lng[c] + lnb[c]);
    }
  }
  __syncthreads();

  // a/b: 4 n-tiles of 64; P and G panels staged together, merged GEMMs share A-fragments
  const int wm = (wv >> 1) * 32, wn = (wv & 1) * 32;
  for (int nt=0; nt<4; nt++){
    { // stage P -> wb rows [0,64), G -> wb rows [64,128)
      const float4* wsP = (const float4*)(w_ab_p + (size_t)nt*64*DPAIR);
      const float4* wsG = (const float4*)(w_ab_g + (size_t)nt*64*DPAIR);
      #pragma unroll
      for (int i=0;i<8;i++){
        int e4 = i*256 + t; int r = e4>>5, c4 = e4&31;
        float4 v = wsP[e4];
        uint2 pk;
        pk.x = cvtpk(v.x, v.y);
        pk.y = cvtpk(v.z, v.w);
        *(uint2*)&wb[r*LDPAD + c4*4] = pk;
      }
      #pragma unroll
      for (int i=0;i<8;i++){
        int e4 = i*256 + t; int r = e4>>5, c4 = e4&31;
        float4 v = wsG[e4];
        uint2 pk;
        pk.x = cvtpk(v.x, v.y);
        pk.y = cvtpk(v.z, v.w);
        *(uint2*)&wb[(64+r)*LDPAD + c4*4] = pk;
      }
    }
    __syncthreads();
    f32x4 accP[2][2] = {}, accG[2][2] = {};
    #pragma unroll
    for (int kk=0;kk<4;kk++){
      bf16x8 aF[2], bP[2], bG[2];
      #pragma unroll
      for (int mi=0;mi<2;mi++) aF[mi] = *(const bf16x8*)&zr[(wm+mi*16+fr)*LDPAD + kk*32 + fq*8];
      #pragma unroll
      for (int ni=0;ni<2;ni++){
        bP[ni] = *(const bf16x8*)&wb[(wn+ni*16+fr)*LDPAD + kk*32 + fq*8];
        bG[ni] = *(const bf16x8*)&wb[(64+wn+ni*16+fr)*LDPAD + kk*32 + fq*8];
      }
      #pragma unroll
      for (int mi=0;mi<2;mi++)
        #pragma unroll
        for (int ni=0;ni<2;ni++){
          accP[mi][ni] = __builtin_amdgcn_mfma_f32_16x16x32_bf16(aF[mi], bP[ni], accP[mi][ni], 0, 0, 0);
          accG[mi][ni] = __builtin_amdgcn_mfma_f32_16x16x32_bf16(aF[mi], bG[ni], accG[mi][ni], 0, 0, 0);
        }
    }
    // epilogue: p*sigmoid(g)*mask, direct d-major 8B stores (no LDS transpose)
    u16* dst = (nt < 2) ? a_t : b_t;
    int dbase = (nt & 1) * 64;
    #pragma unroll
    for (int mi=0;mi<2;mi++){
      int posb = wm + mi*16 + fq*4;
      #pragma unroll
      for (int ni=0;ni<2;ni++){
        int nl   = wn + ni*16 + fr;
        int ng   = nt*64 + nl;
        int drow = dbase + nl;
        float bp  = b_ab_p[ng];
        float bgv = b_ab_g[ng];
        float v0 = (accP[mi][ni][0]+bp) * sigmoidf_(accG[mi][ni][0]+bgv) * msk[posb+0];
        float v1 = (accP[mi][ni][1]+bp) * sigmoidf_(accG[mi][ni][1]+bgv) * msk[posb+1];
        float v2 = (accP[mi][ni][2]+bp) * sigmoidf_(accG[mi][ni][2]+bgv) * msk[posb+2];
        float v3 = (accP[mi][ni][3]+bp) * sigmoidf_(accG[mi][ni][3]+bgv) * msk[posb+3];
        uint2 pk;
        pk.x = (uint32_t)f2bf(v0) | ((uint32_t)f2bf(v1)<<16);
        pk.y = (uint32_t)f2bf(v2) | ((uint32_t)f2bf(v3)<<16);
        *(uint2*)&dst[(size_t)drow*NN + p0 + posb] = pk;
      }
    }
    __syncthreads();   // wb reads complete before next nt's stage
  }
}

// K2: x[i,j,d] = sum_k a[i,k,d]*b[j,k,d] -> 128 GEMMs (512^3) C = A*B^T, both k-contiguous
__global__ __launch_bounds__(256) void k2_einsum(
    const u16* __restrict__ a_t, const u16* __restrict__ b_t, u16* __restrict__ x_t)
{
  __shared__ u16 As[128*40];   // 128 rows x (32 k + 8 pad)
  __shared__ u16 Bs[128*40];
  const int t = threadIdx.x;
  const int d  = blockIdx.z;
  const int i0 = blockIdx.x * 128;
  const int j0 = blockIdx.y * 128;
  const u16* Ag = a_t + (size_t)d*NN + (size_t)i0*NSEQ;
  const u16* Bg = b_t + (size_t)d*NN + (size_t)j0*NSEQ;

  const int lane = t & 63, wv = t >> 6;
  const int wm = (wv >> 1) * 64, wn = (wv & 1) * 64;
  const int fr = lane & 15, fq = lane >> 4;

  f32x4 acc[4][4] = {};

  for (int k0 = 0; k0 < NSEQ; k0 += 32){
    __syncthreads();
    #pragma unroll
    for (int i=0;i<2;i++){
      int e = i*256 + t; int r = e>>2, c8 = e&3;
      uint4 va = *(const uint4*)(Ag + (size_t)r*NSEQ + k0 + c8*8);
      *(uint4*)&As[r*40 + c8*8] = va;
      uint4 vb = *(const uint4*)(Bg + (size_t)r*NSEQ + k0 + c8*8);
      *(uint4*)&Bs[r*40 + c8*8] = vb;
    }
    __syncthreads();
    bf16x8 aF[4], bF[4];
    #pragma unroll
    for (int mi=0;mi<4;mi++) aF[mi] = *(const bf16x8*)&As[(wm + mi*16 + fr)*40 + fq*8];
    #pragma unroll
    for (int ni=0;ni<4;ni++) bF[ni] = *(const bf16x8*)&Bs[(wn + ni*16 + fr)*40 + fq*8];
    #pragma unroll
    for (int mi=0;mi<4;mi++)
      #pragma unroll
      for (int ni=0;ni<4;ni++)
        acc[mi][ni] = __builtin_amdgcn_mfma_f32_16x16x32_bf16(aF[mi], bF[ni], acc[mi][ni], 0, 0, 0);
  }
  u16* Xg = x_t + (size_t)d*NN;
  #pragma unroll
  for (int mi=0;mi<4;mi++)
    #pragma unroll
    for (int ni=0;ni<4;ni++)
      #pragma unroll
      for (int r=0;r<4;r++){
        int row = i0 + wm + mi*16 + fq*4 + r;
        int col = j0 + wn + ni*16 + fr;
        Xg[(size_t)row*NSEQ + col] = f2bf(acc[mi][ni][r]);
      }
}

// K3: out = g * (LN(x) @ w_z^T + b_z), fp32 out
__global__ __launch_bounds__(256) void k3_out(
    const u16* __restrict__ x_t, const u16* __restrict__ g_in,
    const float* __restrict__ w_z, const float* __restrict__ b_z,
    const float* __restrict__ ln_g, const float* __restrict__ ln_b,
    float* __restrict__ out)
{
  __shared__ u16 xs[64*LDPAD];      // 64 pos x 128 d
  __shared__ u16 wz[DPAIR*LDPAD];   // 128 c x 128 d
  __shared__ float lng[DPAIR], lnb[DPAIR], bzs[DPAIR];

  const int t = threadIdx.x;
  const int p0 = blockIdx.x * 64;
  if (t < DPAIR){ lng[t] = ln_g[t]; lnb[t] = ln_b[t]; bzs[t] = b_z[t]; }

  { // stage w_z -> bf16
    const float4* ws = (const float4*)w_z;
    #pragma unroll
    for (int i=0;i<16;i++){
      int e4 = i*256 + t; int r = e4>>5, c4 = e4&31;
      float4 v = ws[e4];
      uint2 pk;
      pk.x = cvtpk(v.x, v.y);
      pk.y = cvtpk(v.z, v.w);
      *(uint2*)&wz[r*LDPAD + c4*4] = pk;
    }
  }
  { // transpose-stage x: xs[pos][d] <- x_t[d][p0+pos] (coalesced 8B global reads)
    #pragma unroll
    for (int i=0;i<8;i++){
      int e = i*256 + t; int dd = e>>4, pc = e&15;
      uint2 v = *(const uint2*)(x_t + (size_t)dd*NN + p0 + pc*4);
      int pb = pc*4;
      xs[(pb+0)*LDPAD + dd] = (u16)(v.x & 0xffffu);
      xs[(pb+1)*LDPAD + dd] = (u16)(v.x >> 16);
      xs[(pb+2)*LDPAD + dd] = (u16)(v.y & 0xffffu);
      xs[(pb+3)*LDPAD + dd] = (u16)(v.y >> 16);
    }
  }
  __syncthreads();
  { // layernorm over d, in place
    int pos = t>>2, q = t&3;
    float s=0.f, s2=0.f;
    #pragma unroll
    for (int j=0;j<32;j++){ float v = bf2f(xs[pos*LDPAD + q*32 + j]); s += v; s2 += v*v; }
    s  += __shfl_xor(s, 1);  s2 += __shfl_xor(s2, 1);
    s  += __shfl_xor(s, 2);  s2 += __shfl_xor(s2, 2);
    float mu  = s * (1.f/128.f);
    float var = s2 * (1.f/128.f) - mu*mu;
    float rs  = rsqrtf(var + 1e-5f);
    #pragma unroll
    for (int j=0;j<32;j++){
      int c = q*32 + j;
      float v = bf2f(xs[pos*LDPAD + c]);
      xs[pos*LDPAD + c] = f2bf((v - mu)*rs*lng[c] + lnb[c]);
    }
  }
  __syncthreads();
  // GEMM: 64 pos x 128 c x 128 d ; wave tile 32x64
  const int lane = t & 63, wv = t >> 6;
  const int wm = (wv >> 1) * 32, wn = (wv & 1) * 64;
  const int fr = lane & 15, fq = lane >> 4;
  f32x4 acc[2][4] = {};
  #pragma unroll
  for (int kk=0;kk<4;kk++){
    bf16x8 aF[2], bF[4];
    #pragma unroll
    for (int mi=0;mi<2;mi++) aF[mi] = *(const bf16x8*)&xs[(wm+mi*16+fr)*LDPAD + kk*32 + fq*8];
    #pragma unroll
    for (int ni=0;ni<4;ni++) bF[ni] = *(const bf16x8*)&wz[(wn+ni*16+fr)*LDPAD + kk*32 + fq*8];
    #pragma unroll
    for (int mi=0;mi<2;mi++)
      #pragma unroll
      for (int ni=0;ni<4;ni++)
        acc[mi][ni] = __builtin_amdgcn_mfma_f32_16x16x32_bf16(aF[mi], bF[ni], acc[mi][ni], 0, 0, 0);
  }
  #pragma unroll
  for (int mi=0;mi<2;mi++)
    #pragma unroll
    for (int ni=0;ni<4;ni++)
      #pragma unroll
      for (int r=0;r<4;r++){
        int pos = wm + mi*16 + fq*4 + r;
        int c   = wn + ni*16 + fr;
        float gv = bf2f(g_in[(size_t)(p0+pos)*DPAIR + c]);
        out[(size_t)(p0+pos)*DPAIR + c] = gv * (acc[mi][ni][r] + bzs[c]);
      }
}

extern "C" void kernel_launch(void* const* d_in, const int* in_sizes, int n_in,
                              void* d_out, int out_size, void* d_ws, size_t ws_size,
                              hipStream_t stream)
{
  const float* z        = (const float*)d_in[0];
  const float* mask     = (const float*)d_in[1];
  const float* w_ab_p   = (const float*)d_in[2];
  const float* b_ab_p   = (const float*)d_in[3];
  const float* w_ab_g   = (const float*)d_in[4];
  const float* b_ab_g   = (const float*)d_in[5];
  const float* w_g      = (const float*)d_in[6];
  const float* b_g      = (const float*)d_in[7];
  const float* w_z      = (const float*)d_in[8];
  const float* b_z      = (const float*)d_in[9];
  const float* ln_in_g  = (const float*)d_in[10];
  const float* ln_in_b  = (const float*)d_in[11];
  const float* ln_out_g = (const float*)d_in[12];
  const float* ln_out_b = (const float*)d_in[13];
  float* out = (float*)d_out;

  const size_t plane = (size_t)DPAIR * NN;            // 33.5M elems
  if (ws_size < 4 * plane * sizeof(u16)) return;      // need 256 MB scratch

  u16* a_t = (u16*)d_ws;            // [128][512][512] bf16, a[i,k,d] -> a_t[d][i*512+k]
  u16* b_t = a_t + plane;           // same, b
  u16* g_b = b_t + plane;           // [pos][128] bf16 gate
  u16* x_t = g_b + plane;           // [128][512][512] bf16 einsum result

  k1_proj<<<dim3(NN/64), dim3(256), 0, stream>>>(
      z, mask, w_ab_p, b_ab_p, w_ab_g, b_ab_g, w_g, b_g, ln_in_g, ln_in_b, a_t, b_t, g_b);
  k2_einsum<<<dim3(4, 4, DPAIR), dim3(256), 0, stream>>>(a_t, b_t, x_t);
  k3_out<<<dim3(NN/64), dim3(256), 0, stream>>>(x_t, g_b, w_z, b_z, ln_out_g, ln_out_b, out);
}

// Round 6
// 542.773 us; speedup vs baseline: 1.0498x; 1.0457x over previous
//
#include <hip/hip_runtime.h>
#include <stdint.h>

#define NSEQ 512
#define DPAIR 128
#define NN (NSEQ*NSEQ)        // 262144 positions
#define LDPAD 136             // 128 + 8 pad: keeps 16B ds alignment, ~2-way conflicts max

typedef unsigned short u16;
typedef __attribute__((ext_vector_type(8))) short bf16x8;   // 8 bf16 = 4 VGPRs
typedef __attribute__((ext_vector_type(4))) float f32x4;

__device__ __forceinline__ float bf2f(u16 h){ return __uint_as_float(((uint32_t)h)<<16); }
__device__ __forceinline__ u16 f2bf(float f){
  uint32_t u = __float_as_uint(f);
  u += 0x7fffu + ((u>>16)&1u);          // RNE
  return (u16)(u>>16);
}
// HW packed f32->bf16 (RNE), 1 VALU op per 2 elements; bit-identical to f2bf for finite inputs
__device__ __forceinline__ uint32_t cvtpk(float lo, float hi){
  uint32_t r;
  asm("v_cvt_pk_bf16_f32 %0, %1, %2" : "=v"(r) : "v"(lo), "v"(hi));
  return r;
}
__device__ __forceinline__ float sigmoidf_(float x){ return 1.0f/(1.0f+__expf(-x)); }

// stage 64 rows x 128 cols of fp32 (row-major, k contiguous) -> bf16 LDS [64][LDPAD]
__device__ __forceinline__ void stage_w64(const float* __restrict__ src, u16* wb, int t){
  const float4* ws = (const float4*)src;
  #pragma unroll
  for (int i=0;i<8;i++){
    int e4 = i*256 + t; int r = e4>>5, c4 = e4&31;
    float4 v = ws[e4];
    uint2 pk;
    pk.x = cvtpk(v.x, v.y);
    pk.y = cvtpk(v.z, v.w);
    *(uint2*)&wb[r*LDPAD + c4*4] = pk;
  }
}

// 64x64x128 GEMM: D[pos][n] = sum_k A[pos][k]*W[n][k]; per-wave 32x32 tile (2x2 MFMAs x 4 k-steps)
__device__ __forceinline__ void gemm_64x64(const u16* A, const u16* W,
                                           int wm, int wn, int fr, int fq,
                                           f32x4 (&acc)[2][2]){
  #pragma unroll
  for (int kk=0;kk<4;kk++){
    bf16x8 aF[2], bF[2];
    #pragma unroll
    for (int mi=0;mi<2;mi++) aF[mi] = *(const bf16x8*)(A + (wm+mi*16+fr)*LDPAD + kk*32 + fq*8);
    #pragma unroll
    for (int ni=0;ni<2;ni++) bF[ni] = *(const bf16x8*)(W + (wn+ni*16+fr)*LDPAD + kk*32 + fq*8);
    #pragma unroll
    for (int mi=0;mi<2;mi++)
      #pragma unroll
      for (int ni=0;ni<2;ni++)
        acc[mi][ni] = __builtin_amdgcn_mfma_f32_16x16x32_bf16(aF[mi], bF[ni], acc[mi][ni], 0, 0, 0);
  }
}

// K1: gate gemm in 2 halves (raw z) -> in-place LN -> P,G gemms per nt -> direct a/b stores
// LDS = zr(17.4K) + wb(17.4K) + misc ~1.1K = 35.9 KB -> 4 blocks/CU (16 waves), was 3 (12 waves)
__global__ __launch_bounds__(256) void k1_proj(
    const float* __restrict__ z, const float* __restrict__ mask,
    const float* __restrict__ w_ab_p, const float* __restrict__ b_ab_p,
    const float* __restrict__ w_ab_g, const float* __restrict__ b_ab_g,
    const float* __restrict__ w_g, const float* __restrict__ b_g,
    const float* __restrict__ ln_g, const float* __restrict__ ln_b,
    u16* __restrict__ a_t, u16* __restrict__ b_t, u16* __restrict__ g_out)
{
  __shared__ u16 zr[64*LDPAD];     // z tile, bf16 (raw, then LN'd in place)
  __shared__ u16 wb[64*LDPAD];     // one 64-row weight panel at a time
  __shared__ float lng[DPAIR], lnb[DPAIR], msk[64];

  const int t = threadIdx.x;
  const int p0 = blockIdx.x * 64;
  const int lane = t & 63, wv = t >> 6;
  const int wm = (wv >> 1) * 32, wn = (wv & 1) * 32;
  const int fr = lane & 15, fq = lane >> 4;

  if (t < DPAIR){ lng[t] = ln_g[t]; lnb[t] = ln_b[t]; }
  else if (t < DPAIR + 64) msk[t - DPAIR] = mask[p0 + t - DPAIR];

  { // stage raw z tile (64 pos x 128 ch, contiguous) -> bf16
    const float4* zs = (const float4*)(z + (size_t)p0 * DPAIR);
    #pragma unroll
    for (int i=0;i<8;i++){
      int e4 = i*256 + t; int pos = e4>>5, c4 = e4&31;
      float4 v = zs[e4];
      uint2 pk;
      pk.x = cvtpk(v.x, v.y);
      pk.y = cvtpk(v.z, v.w);
      *(uint2*)&zr[pos*LDPAD + c4*4] = pk;
    }
  }
  // gate g = sigmoid(z @ w_g^T + b_g) in two 64-column halves, raw-z input
  stage_w64(w_g, wb, t);
  __syncthreads();
  #pragma unroll
  for (int h=0; h<2; h++){
    f32x4 acc[2][2] = {};
    gemm_64x64(zr, wb, wm, wn, fr, fq, acc);
    #pragma unroll
    for (int mi=0;mi<2;mi++)
      #pragma unroll
      for (int ni=0;ni<2;ni++){
        int ng = h*64 + wn + ni*16 + fr;
        float bg = b_g[ng];
        #pragma unroll
        for (int r=0;r<4;r++){
          int pos = wm + mi*16 + fq*4 + r;
          g_out[(size_t)(p0+pos)*DPAIR + ng] = f2bf(sigmoidf_(acc[mi][ni][r] + bg));
        }
      }
    __syncthreads();
    if (h == 0){
      stage_w64(w_g + 64*DPAIR, wb, t);
      __syncthreads();
    }
  }

  { // layernorm in place on zr ; 4 threads per position (gate reads of zr complete)
    int pos = t>>2, q = t&3;
    float s=0.f, s2=0.f;
    #pragma unroll
    for (int j=0;j<32;j++){ float v = bf2f(zr[pos*LDPAD + q*32 + j]); s += v; s2 += v*v; }
    s  += __shfl_xor(s, 1);  s2 += __shfl_xor(s2, 1);
    s  += __shfl_xor(s, 2);  s2 += __shfl_xor(s2, 2);
    float mu  = s * (1.f/128.f);
    float var = s2 * (1.f/128.f) - mu*mu;
    float rs  = rsqrtf(var + 1e-5f);
    #pragma unroll
    for (int j=0;j<32;j++){
      int c = q*32 + j;
      float v = bf2f(zr[pos*LDPAD + c]);
      zr[pos*LDPAD + c] = f2bf((v - mu)*rs*lng[c] + lnb[c]);
    }
  }
  __syncthreads();

  // a/b: 4 n-tiles of 64 (nt 0,1 -> a ; 2,3 -> b); P then G staged sequentially in 64-row wb
  for (int nt=0; nt<4; nt++){
    stage_w64(w_ab_p + (size_t)nt*64*DPAIR, wb, t);
    __syncthreads();
    f32x4 accP[2][2] = {};
    gemm_64x64(zr, wb, wm, wn, fr, fq, accP);
    __syncthreads();
    stage_w64(w_ab_g + (size_t)nt*64*DPAIR, wb, t);
    __syncthreads();
    f32x4 accG[2][2] = {};
    gemm_64x64(zr, wb, wm, wn, fr, fq, accG);
    // epilogue: p*sigmoid(g)*mask, direct d-major 8B stores
    u16* dst = (nt < 2) ? a_t : b_t;
    int dbase = (nt & 1) * 64;
    #pragma unroll
    for (int mi=0;mi<2;mi++){
      int posb = wm + mi*16 + fq*4;
      #pragma unroll
      for (int ni=0;ni<2;ni++){
        int nl   = wn + ni*16 + fr;
        int ng   = nt*64 + nl;
        int drow = dbase + nl;
        float bp  = b_ab_p[ng];
        float bgv = b_ab_g[ng];
        float v0 = (accP[mi][ni][0]+bp) * sigmoidf_(accG[mi][ni][0]+bgv) * msk[posb+0];
        float v1 = (accP[mi][ni][1]+bp) * sigmoidf_(accG[mi][ni][1]+bgv) * msk[posb+1];
        float v2 = (accP[mi][ni][2]+bp) * sigmoidf_(accG[mi][ni][2]+bgv) * msk[posb+2];
        float v3 = (accP[mi][ni][3]+bp) * sigmoidf_(accG[mi][ni][3]+bgv) * msk[posb+3];
        uint2 pk;
        pk.x = (uint32_t)f2bf(v0) | ((uint32_t)f2bf(v1)<<16);
        pk.y = (uint32_t)f2bf(v2) | ((uint32_t)f2bf(v3)<<16);
        *(uint2*)&dst[(size_t)drow*NN + p0 + posb] = pk;
      }
    }
    __syncthreads();   // all waves' wb reads complete before next nt's stage
  }
}

// K2: x[i,j,d] = sum_k a[i,k,d]*b[j,k,d] -> 128 GEMMs (512^3) C = A*B^T, both k-contiguous
__global__ __launch_bounds__(256) void k2_einsum(
    const u16* __restrict__ a_t, const u16* __restrict__ b_t, u16* __restrict__ x_t)
{
  __shared__ u16 As[128*40];   // 128 rows x (32 k + 8 pad)
  __shared__ u16 Bs[128*40];
  const int t = threadIdx.x;
  const int d  = blockIdx.z;
  const int i0 = blockIdx.x * 128;
  const int j0 = blockIdx.y * 128;
  const u16* Ag = a_t + (size_t)d*NN + (size_t)i0*NSEQ;
  const u16* Bg = b_t + (size_t)d*NN + (size_t)j0*NSEQ;

  const int lane = t & 63, wv = t >> 6;
  const int wm = (wv >> 1) * 64, wn = (wv & 1) * 64;
  const int fr = lane & 15, fq = lane >> 4;

  f32x4 acc[4][4] = {};

  for (int k0 = 0; k0 < NSEQ; k0 += 32){
    __syncthreads();
    #pragma unroll
    for (int i=0;i<2;i++){
      int e = i*256 + t; int r = e>>2, c8 = e&3;
      uint4 va = *(const uint4*)(Ag + (size_t)r*NSEQ + k0 + c8*8);
      *(uint4*)&As[r*40 + c8*8] = va;
      uint4 vb = *(const uint4*)(Bg + (size_t)r*NSEQ + k0 + c8*8);
      *(uint4*)&Bs[r*40 + c8*8] = vb;
    }
    __syncthreads();
    bf16x8 aF[4], bF[4];
    #pragma unroll
    for (int mi=0;mi<4;mi++) aF[mi] = *(const bf16x8*)&As[(wm + mi*16 + fr)*40 + fq*8];
    #pragma unroll
    for (int ni=0;ni<4;ni++) bF[ni] = *(const bf16x8*)&Bs[(wn + ni*16 + fr)*40 + fq*8];
    #pragma unroll
    for (int mi=0;mi<4;mi++)
      #pragma unroll
      for (int ni=0;ni<4;ni++)
        acc[mi][ni] = __builtin_amdgcn_mfma_f32_16x16x32_bf16(aF[mi], bF[ni], acc[mi][ni], 0, 0, 0);
  }
  u16* Xg = x_t + (size_t)d*NN;
  #pragma unroll
  for (int mi=0;mi<4;mi++)
    #pragma unroll
    for (int ni=0;ni<4;ni++)
      #pragma unroll
      for (int r=0;r<4;r++){
        int row = i0 + wm + mi*16 + fq*4 + r;
        int col = j0 + wn + ni*16 + fr;
        Xg[(size_t)row*NSEQ + col] = f2bf(acc[mi][ni][r]);
      }
}

// K3: out = g * (LN(x) @ w_z^T + b_z), fp32 out
__global__ __launch_bounds__(256) void k3_out(
    const u16* __restrict__ x_t, const u16* __restrict__ g_in,
    const float* __restrict__ w_z, const float* __restrict__ b_z,
    const float* __restrict__ ln_g, const float* __restrict__ ln_b,
    float* __restrict__ out)
{
  __shared__ u16 xs[64*LDPAD];      // 64 pos x 128 d
  __shared__ u16 wz[DPAIR*LDPAD];   // 128 c x 128 d
  __shared__ float lng[DPAIR], lnb[DPAIR], bzs[DPAIR];

  const int t = threadIdx.x;
  const int p0 = blockIdx.x * 64;
  if (t < DPAIR){ lng[t] = ln_g[t]; lnb[t] = ln_b[t]; bzs[t] = b_z[t]; }

  { // stage w_z -> bf16
    const float4* ws = (const float4*)w_z;
    #pragma unroll
    for (int i=0;i<16;i++){
      int e4 = i*256 + t; int r = e4>>5, c4 = e4&31;
      float4 v = ws[e4];
      uint2 pk;
      pk.x = cvtpk(v.x, v.y);
      pk.y = cvtpk(v.z, v.w);
      *(uint2*)&wz[r*LDPAD + c4*4] = pk;
    }
  }
  { // transpose-stage x: xs[pos][d] <- x_t[d][p0+pos] (coalesced 8B global reads)
    #pragma unroll
    for (int i=0;i<8;i++){
      int e = i*256 + t; int dd = e>>4, pc = e&15;
      uint2 v = *(const uint2*)(x_t + (size_t)dd*NN + p0 + pc*4);
      int pb = pc*4;
      xs[(pb+0)*LDPAD + dd] = (u16)(v.x & 0xffffu);
      xs[(pb+1)*LDPAD + dd] = (u16)(v.x >> 16);
      xs[(pb+2)*LDPAD + dd] = (u16)(v.y & 0xffffu);
      xs[(pb+3)*LDPAD + dd] = (u16)(v.y >> 16);
    }
  }
  __syncthreads();
  { // layernorm over d, in place
    int pos = t>>2, q = t&3;
    float s=0.f, s2=0.f;
    #pragma unroll
    for (int j=0;j<32;j++){ float v = bf2f(xs[pos*LDPAD + q*32 + j]); s += v; s2 += v*v; }
    s  += __shfl_xor(s, 1);  s2 += __shfl_xor(s2, 1);
    s  += __shfl_xor(s, 2);  s2 += __shfl_xor(s2, 2);
    float mu  = s * (1.f/128.f);
    float var = s2 * (1.f/128.f) - mu*mu;
    float rs  = rsqrtf(var + 1e-5f);
    #pragma unroll
    for (int j=0;j<32;j++){
      int c = q*32 + j;
      float v = bf2f(xs[pos*LDPAD + c]);
      xs[pos*LDPAD + c] = f2bf((v - mu)*rs*lng[c] + lnb[c]);
    }
  }
  __syncthreads();
  // GEMM: 64 pos x 128 c x 128 d ; wave tile 32x64
  const int lane = t & 63, wv = t >> 6;
  const int wm = (wv >> 1) * 32, wn = (wv & 1) * 64;
  const int fr = lane & 15, fq = lane >> 4;
  f32x4 acc[2][4] = {};
  #pragma unroll
  for (int kk=0;kk<4;kk++){
    bf16x8 aF[2], bF[4];
    #pragma unroll
    for (int mi=0;mi<2;mi++) aF[mi] = *(const bf16x8*)&xs[(wm+mi*16+fr)*LDPAD + kk*32 + fq*8];
    #pragma unroll
    for (int ni=0;ni<4;ni++) bF[ni] = *(const bf16x8*)&wz[(wn+ni*16+fr)*LDPAD + kk*32 + fq*8];
    #pragma unroll
    for (int mi=0;mi<2;mi++)
      #pragma unroll
      for (int ni=0;ni<4;ni++)
        acc[mi][ni] = __builtin_amdgcn_mfma_f32_16x16x32_bf16(aF[mi], bF[ni], acc[mi][ni], 0, 0, 0);
  }
  #pragma unroll
  for (int mi=0;mi<2;mi++)
    #pragma unroll
    for (int ni=0;ni<4;ni++)
      #pragma unroll
      for (int r=0;r<4;r++){
        int pos = wm + mi*16 + fq*4 + r;
        int c   = wn + ni*16 + fr;
        float gv = bf2f(g_in[(size_t)(p0+pos)*DPAIR + c]);
        out[(size_t)(p0+pos)*DPAIR + c] = gv * (acc[mi][ni][r] + bzs[c]);
      }
}

extern "C" void kernel_launch(void* const* d_in, const int* in_sizes, int n_in,
                              void* d_out, int out_size, void* d_ws, size_t ws_size,
                              hipStream_t stream)
{
  const float* z        = (const float*)d_in[0];
  const float* mask     = (const float*)d_in[1];
  const float* w_ab_p   = (const float*)d_in[2];
  const float* b_ab_p   = (const float*)d_in[3];
  const float* w_ab_g   = (const float*)d_in[4];
  const float* b_ab_g   = (const float*)d_in[5];
  const float* w_g      = (const float*)d_in[6];
  const float* b_g      = (const float*)d_in[7];
  const float* w_z      = (const float*)d_in[8];
  const float* b_z      = (const float*)d_in[9];
  const float* ln_in_g  = (const float*)d_in[10];
  const float* ln_in_b  = (const float*)d_in[11];
  const float* ln_out_g = (const float*)d_in[12];
  const float* ln_out_b = (const float*)d_in[13];
  float* out = (float*)d_out;

  const size_t plane = (size_t)DPAIR * NN;            // 33.5M elems
  if (ws_size < 4 * plane * sizeof(u16)) return;      // need 256 MB scratch

  u16* a_t = (u16*)d_ws;            // [128][512][512] bf16, a[i,k,d] -> a_t[d][i*512+k]
  u16* b_t = a_t + plane;           // same, b
  u16* g_b = b_t + plane;           // [pos][128] bf16 gate
  u16* x_t = g_b + plane;           // [128][512][512] bf16 einsum result

  k1_proj<<<dim3(NN/64), dim3(256), 0, stream>>>(
      z, mask, w_ab_p, b_ab_p, w_ab_g, b_ab_g, w_g, b_g, ln_in_g, ln_in_b, a_t, b_t, g_b);
  k2_einsum<<<dim3(4, 4, DPAIR), dim3(256), 0, stream>>>(a_t, b_t, x_t);
  k3_out<<<dim3(NN/64), dim3(256), 0, stream>>>(x_t, g_b, w_z, b_z, ln_out_g, ln_out_b, out);
}